// Round 7
// baseline (432.706 us; speedup 1.0000x reference)
//
#include <hip/hip_runtime.h>
#include <stdint.h>

#define JAX_PARTITIONABLE 1
#define NB 1024

// ---------- helpers ----------
__device__ __forceinline__ float tanh_f(float x) {
  float e = __expf(2.0f * x);
  return 1.0f - 2.0f / (e + 1.0f);
}
__device__ __forceinline__ float sigm(float x) {
  return 1.0f / (1.0f + __expf(-x));
}

// Workspace stores: agent-scope relaxed atomic stores (sc1 write-through to the
// coherent memory side). Consumers use PLAIN loads after the barrier; first touch
// of each line is always post-barrier (write-once-then-read dataflow), hence fresh.
__device__ __forceinline__ void stw(float* p, float v) {
  __hip_atomic_store(p, v, __ATOMIC_RELAXED, __HIP_MEMORY_SCOPE_AGENT);
}
__device__ __forceinline__ void stw4(float* p, float4 v) {
  union { float2 f; uint64_t u; } a, b;
  a.f.x = v.x; a.f.y = v.y; b.f.x = v.z; b.f.y = v.w;
  __hip_atomic_store((uint64_t*)p, a.u, __ATOMIC_RELAXED, __HIP_MEMORY_SCOPE_AGENT);
  __hip_atomic_store(((uint64_t*)p) + 1, b.u, __ATOMIC_RELAXED, __HIP_MEMORY_SCOPE_AGENT);
}

// ---------- Threefry-2x32 (JAX-compatible) ----------
__device__ __forceinline__ void tf2x32(unsigned k0, unsigned k1, unsigned x0, unsigned x1,
                                       unsigned &o0, unsigned &o1) {
  unsigned ks0 = k0, ks1 = k1, ks2 = k0 ^ k1 ^ 0x1BD11BDAu;
  x0 += ks0; x1 += ks1;
#define RR(r) { x0 += x1; x1 = (x1 << r) | (x1 >> (32 - r)); x1 ^= x0; }
  RR(13) RR(15) RR(26) RR(6)  x0 += ks1; x1 += ks2 + 1u;
  RR(17) RR(29) RR(16) RR(24) x0 += ks2; x1 += ks0 + 2u;
  RR(13) RR(15) RR(26) RR(6)  x0 += ks0; x1 += ks1 + 3u;
  RR(17) RR(29) RR(16) RR(24) x0 += ks1; x1 += ks2 + 4u;
  RR(13) RR(15) RR(26) RR(6)  x0 += ks2; x1 += ks0 + 5u;
#undef RR
  o0 = x0; o1 = x1;
}

__device__ __forceinline__ float drop_scale(unsigned k0, unsigned k1, unsigned flat) {
#if JAX_PARTITIONABLE
  unsigned o0, o1; tf2x32(k0, k1, 0u, flat, o0, o1);
  unsigned bits = o0 ^ o1;
#else
  unsigned o0, o1, bits;
  if (flat < 8192u) { tf2x32(k0, k1, flat, flat + 8192u, o0, o1); bits = o0; }
  else             { tf2x32(k0, k1, flat - 8192u, flat, o0, o1); bits = o1; }
#endif
  return (bits >> 31) ? 0.0f : 2.0f;
}
__device__ __forceinline__ void get_drop_keys(unsigned &a0, unsigned &a1,
                                              unsigned &b0, unsigned &b1) {
#if JAX_PARTITIONABLE
  tf2x32(0u, 42u, 0u, 0u, a0, a1);
  tf2x32(0u, 42u, 0u, 1u, b0, b1);
#else
  unsigned p0, q0, p1, q1;
  tf2x32(0u, 42u, 0u, 2u, p0, q0);
  tf2x32(0u, 42u, 1u, 3u, p1, q1);
  a0 = p0; a1 = p1; b0 = q0; b1 = q1;
#endif
}

// ---------- fence-free device barrier (1024 blocks: 32 groups x 32) ----------
__device__ __forceinline__ void gbar(int* ibase, int phase) {
  __syncthreads();
  if (threadIdx.x == 0) {
    const int s = (int)(blockIdx.x & 31);
    int* sub   = ibase + s * 64;
    int* top   = ibase + 2048;
    int* flags = ibase + 2112;
    int old = __hip_atomic_fetch_add(sub, 1, __ATOMIC_RELAXED, __HIP_MEMORY_SCOPE_AGENT);
    if (old == phase * 32 - 1) {
      int t = __hip_atomic_fetch_add(top, 1, __ATOMIC_RELAXED, __HIP_MEMORY_SCOPE_AGENT);
      if (t == phase * 32 - 1) {
        #pragma unroll
        for (int i = 0; i < 32; i++)
          __hip_atomic_store(flags + i * 64, phase, __ATOMIC_RELAXED, __HIP_MEMORY_SCOPE_AGENT);
      }
    }
    long long guard = 0;
    while (__hip_atomic_load(flags + s * 64, __ATOMIC_RELAXED, __HIP_MEMORY_SCOPE_AGENT) < phase) {
      __builtin_amdgcn_s_sleep(4);
      if (++guard > (1LL << 21)) break;
    }
  }
  __syncthreads();
}

// =================================================================
// k0: zero barrier counters + flags (ws is poisoned between iterations)
// =================================================================
__global__ void k0(int* cnt) {
  for (int i = threadIdx.x; i < 4160; i += 256) cnt[i] = 0;
}

// =================================================================
// kM: whole decoder step, 9 phases / 8 grid barriers, 1024 blocks (4/CU)
// Activations packed as [k/4][b][4]: lane b loads float4 of 4 consecutive k.
// =================================================================
__global__ __launch_bounds__(256, 4) void kM(
    const float* es, const float* esp, const float* prenet_in,
    const float* rnn1_hidden, const float* rnn2_hidden,
    const float* rnn1_cell, const float* rnn2_cell,
    const float* context_vec, const float* attn_hidden, const int* chars,
    const float* conv_b, const float* L_w, const float* W_w, const float* W_b, const float* v_w,
    const float* fc1_w, const float* fc1_b, const float* fc2_w, const float* fc2_b,
    const float* gru_w_ih, const float* gru_w_hh, const float* gru_b_ih, const float* gru_b_hh,
    const float* ri_w, const float* ri_b,
    const float* l1_w_ih, const float* l1_w_hh, const float* l1_b_ih, const float* l1_b_hh,
    const float* l2_w_ih, const float* l2_w_hh, const float* l2_b_ih, const float* l2_b_hh,
    const float* mp_w, const float* sp_w, const float* sp_b,
    float* ws,
    float* mels_o, float* scores_o, float* attn_o, float* h1_o, float* h2_o,
    float* c1_o, float* c2_o, float* ctx_o, float* stop_o) {
  int* ibase = (int*)ws;            // 4160 ints: 32x64 sub + 64 top + 32x64 flags
  float* pqc    = ws + 4160;        // 128
  float* phq    = ws + 4288;        // 16384  [64][64][4]
  float* poq    = ws + 20672;       // 16384
  float* ahq_h  = ws + 37056;       // 8192   [32][64][4] attn_h (GRU out)
  float* u_buf  = ws + 45248;       // 65536
  float* ctxq   = ws + 110784;      // 32768  [128][64][4] (atomic-accum; zeroed P1)
  float* xq     = ws + 143552;      // 32768
  float* x2q    = ws + 176320;      // 32768
  float* x3q    = ws + 209088;      // 32768
  float* hq1    = ws + 241856;      // 32768
  float* hq2    = ws + 274624;      // 32768
  float* cvq    = ws + 307392;      // 32768
  float* ahq_in = ws + 340160;      // 8192
  float* c1pT   = ws + 348352;      // 32768  [k][b]
  float* c2pT   = ws + 381120;      // 32768

  const float4* cvq4   = (const float4*)cvq;
  const float4* phq4   = (const float4*)phq;
  const float4* poq4   = (const float4*)poq;
  const float4* ahq_in4= (const float4*)ahq_in;
  const float4* ahq_h4 = (const float4*)ahq_h;
  const float4* ctxq4  = (const float4*)ctxq;
  const float4* xq4    = (const float4*)xq;
  const float4* x2q4   = (const float4*)x2q;
  const float4* x3q4   = (const float4*)x3q;
  const float4* hq14   = (const float4*)hq1;
  const float4* hq24   = (const float4*)hq2;

  const int g = blockIdx.x, tid = threadIdx.x;
  const int w = tid >> 6, lane = tid & 63;
  __shared__ float sh[5440];        // 21.8 KB -> 4 blocks/CU co-resident

  // ---------------- P1: fc1 + packed transposes + zero ctxq + pqc + warm es A ----------------
  if (g < 64) {
    for (int i = tid; i < 5120; i += 256) sh[(i / 80) * 81 + (i % 80)] = prenet_in[i];
    __syncthreads();
    unsigned d1k0, d1k1, d2k0, d2k1;
    get_drop_keys(d1k0, d1k1, d2k0, d2k1);
    const int j = g * 4 + w;
    float acc = fc1_b[j];
    const float* wr = fc1_w + j * 80;
    #pragma unroll 8
    for (int k = 0; k < 80; k += 2) {
      float2 wv = *(const float2*)(wr + k);
      acc += sh[lane * 81 + k] * wv.x + sh[lane * 81 + k + 1] * wv.y;
    }
    acc = fmaxf(acc, 0.0f) * drop_scale(d1k0, d1k1, (unsigned)(lane * 256 + j));
    stw(&phq[g * 256 + lane * 4 + w], acc);
  } else if (g < 96) {          // hq1
    int t = (g - 64) * 256 + tid;
    int k4 = t >> 6, b = t & 63;
    stw4(&hq1[k4 * 256 + b * 4], ((const float4*)rnn1_hidden)[b * 128 + k4]);
  } else if (g < 128) {         // hq2
    int t = (g - 96) * 256 + tid;
    int k4 = t >> 6, b = t & 63;
    stw4(&hq2[k4 * 256 + b * 4], ((const float4*)rnn2_hidden)[b * 128 + k4]);
  } else if (g < 160) {         // cvq
    int t = (g - 128) * 256 + tid;
    int k4 = t >> 6, b = t & 63;
    stw4(&cvq[k4 * 256 + b * 4], ((const float4*)context_vec)[b * 128 + k4]);
  } else if (g < 168) {         // ahq_in
    int t = (g - 160) * 256 + tid;
    int k4 = t >> 6, b = t & 63;
    stw4(&ahq_in[k4 * 256 + b * 4], ((const float4*)attn_hidden)[b * 32 + k4]);
  } else if (g < 232) {         // c1pT [k][b]
    int base = (g - 168) * 512;
    #pragma unroll
    for (int e = 0; e < 2; e++) { int i = base + tid + e * 256; stw(&c1pT[i], rnn1_cell[(i & 63) * 512 + (i >> 6)]); }
  } else if (g < 296) {         // c2pT
    int base = (g - 232) * 512;
    #pragma unroll
    for (int e = 0; e < 2; e++) { int i = base + tid + e * 256; stw(&c2pT[i], rnn2_cell[(i & 63) * 512 + (i >> 6)]); }
  } else if (g < 360) {         // zero ctxq
    int base = (g - 296) * 512;
    #pragma unroll
    for (int e = 0; e < 2; e++) stw(&ctxq[base + tid + e * 256], 0.0f);
  } else if (g == 360) {        // pqc
    if (tid < 128) {
      float acc = W_b[tid];
      const float* lw = L_w + tid * 32;
      #pragma unroll
      for (int f = 0; f < 32; f++) acc += conv_b[f] * lw[f];
      stw(&pqc[tid], acc);
    }
  } else {                      // warm es part A: 663 blocks, lines 0..678911
    const unsigned wi0 = (unsigned)((g - 361) * 256 + tid);   // 0..169727
    float acc = 0.0f;
    #pragma unroll
    for (int s = 0; s < 4; s++) acc += es[(size_t)(wi0 + (unsigned)s * 169728u) * 32];
    asm volatile("" :: "v"(acc));
  }
  gbar(ibase, 1);

  // ---------------- P2: fc2 | warm esp + all downstream weights ----------------
  if (g < 64) {
    const int j = g * 4 + w;
    ((float4*)(sh + w * 256))[lane] = ((const float4*)(fc2_w + j * 256))[lane];
    __syncthreads();
    unsigned d1k0, d1k1, d2k0, d2k1;
    get_drop_keys(d1k0, d1k1, d2k0, d2k1);
    const float4* wv4 = (const float4*)(sh + w * 256);
    float acc = fc2_b[j];
    #pragma unroll 8
    for (int k4 = 0; k4 < 64; k4++) {
      float4 x4 = phq4[k4 * 64 + lane];
      float4 wv = wv4[k4];
      acc += x4.x * wv.x + x4.y * wv.y + x4.z * wv.z + x4.w * wv.w;
    }
    acc = fmaxf(acc, 0.0f) * drop_scale(d2k0, d2k1, (unsigned)(lane * 256 + j));
    stw(&poq[g * 256 + lane * 4 + w], acc);
  } else {
    const unsigned wid = (unsigned)((g - 64) * 256 + tid);   // 0..245759
    float acc = 0.0f;
    acc += esp[(size_t)wid * 32];
    if (wid < 16384u) acc += esp[(size_t)(wid + 245760u) * 32];
    if (wid < 32768u) {
      acc += l1_w_ih[(size_t)wid * 32];
      acc += l1_w_hh[(size_t)wid * 32];
      acc += l2_w_ih[(size_t)wid * 32];
      acc += l2_w_hh[(size_t)wid * 32];
    }
    if (wid < 10240u) acc += ri_w[(size_t)wid * 32];
    if (wid < 9216u)  acc += gru_w_ih[(size_t)wid * 32];
    if (wid < 1536u)  acc += gru_w_hh[(size_t)wid * 32];
    if (wid < 512u)   acc += W_w[(size_t)wid * 32];
    if (wid < 2048u)  acc += (float)chars[(size_t)wid * 32];
    if (wid < 1280u)  acc += mp_w[(size_t)(wid >> 4) * 10240 + (wid & 15) * 32];
    if (wid < 32u)    acc += sp_w[(size_t)wid * 32];
    asm volatile("" :: "v"(acc));
  }
  gbar(ibase, 2);

  // ---------------- P3: GRU mm + gates fused (blocks 0-127) | warm es part B ----------------
  if (g < 128) {
    if (w < 3) {
      const int rj = g + 128 * w;
      const float4* src = (const float4*)(gru_w_ih + (size_t)rj * 768);
      float4* dst = (float4*)(sh + w * 768);
      #pragma unroll
      for (int q = 0; q < 3; q++) dst[q * 64 + lane] = src[q * 64 + lane];
    } else {
      float4* dst = (float4*)(sh + 2304);
      if (lane < 32) {
        dst[lane]      = ((const float4*)gru_w_hh)[(size_t)g * 32 + lane];
        dst[32 + lane] = ((const float4*)gru_w_hh)[(size_t)(128 + g) * 32 + lane];
        dst[64 + lane] = ((const float4*)gru_w_hh)[(size_t)(256 + g) * 32 + lane];
      }
    }
    __syncthreads();
    if (w < 3) {
      const int rj = g + 128 * w;
      const float4* wv4 = (const float4*)(sh + w * 768);
      float acc = gru_b_ih[rj];
      #pragma unroll 4
      for (int k4 = 0; k4 < 128; k4++) {
        float4 x4 = cvq4[k4 * 64 + lane];
        float4 wv = wv4[k4];
        acc += x4.x * wv.x + x4.y * wv.y + x4.z * wv.z + x4.w * wv.w;
      }
      #pragma unroll 4
      for (int k4 = 0; k4 < 64; k4++) {
        float4 x4 = poq4[k4 * 64 + lane];
        float4 wv = wv4[128 + k4];
        acc += x4.x * wv.x + x4.y * wv.y + x4.z * wv.z + x4.w * wv.w;
      }
      sh[2688 + w * 64 + lane] = acc;
    } else {
      const float4* wh4 = (const float4*)(sh + 2304);
      #pragma unroll
      for (int r = 0; r < 3; r++) {
        float acc = gru_b_hh[r * 128 + g];
        #pragma unroll 4
        for (int k4 = 0; k4 < 32; k4++) {
          float4 x4 = ahq_in4[k4 * 64 + lane];
          float4 wv = wh4[r * 32 + k4];
          acc += x4.x * wv.x + x4.y * wv.y + x4.z * wv.z + x4.w * wv.w;
        }
        sh[2688 + (3 + r) * 64 + lane] = acc;
      }
    }
    __syncthreads();
    if (tid < 64) {
      float gr = sh[2688 + tid]       + sh[2688 + 192 + tid];
      float gz = sh[2688 + 64 + tid]  + sh[2688 + 256 + tid];
      float gin = sh[2688 + 128 + tid];
      float ghn = sh[2688 + 320 + tid];
      float a0 = ahq_in[(g >> 2) * 256 + tid * 4 + (g & 3)];
      float r = sigm(gr), z = sigm(gz);
      float h = (1.0f - z) * tanh_f(gin + r * ghn) + z * a0;
      stw(&ahq_h[(g >> 2) * 256 + tid * 4 + (g & 3)], h);
      attn_o[tid * 128 + g] = h;
    }
  } else {                      // warm es part B: lines 678912..1048575
    const unsigned wid = (unsigned)((g - 128) * 256 + tid);   // 0..229375
    float acc = 0.0f;
    acc += es[(size_t)(678912u + wid) * 32];
    if (wid < 140288u) acc += es[(size_t)(908288u + wid) * 32];
    asm volatile("" :: "v"(acc));
  }
  gbar(ibase, 3);

  // ---------------- P4: per-lane pq + u (16 chunks of 64 t) ----------------
  {
    const int b = g >> 4, tch = g & 15;
    float* shh = sh;           // 128
    float* pqs = sh + 128;     // 128
    if (tid < 128) shh[tid] = ahq_h[(tid >> 2) * 256 + b * 4 + (tid & 3)];
    __syncthreads();
    if (tid < 128) {
      const int n = tid;
      float acc = pqc[n];
      const float4* wr = (const float4*)(W_w + n * 128);
      #pragma unroll 8
      for (int k4 = 0; k4 < 32; k4++) {
        float4 wv = wr[k4];
        acc += shh[k4 * 4] * wv.x + shh[k4 * 4 + 1] * wv.y + shh[k4 * 4 + 2] * wv.z + shh[k4 * 4 + 3] * wv.w;
      }
      pqs[n] = acc;
    }
    __syncthreads();
    float2 p = *(const float2*)(pqs + 2 * lane);
    float2 v2 = *(const float2*)(v_w + 2 * lane);
    const int tb = tch * 64 + w * 16;
    const float* erow = esp + ((size_t)b * 1024 + tb) * 128 + 2 * lane;
    for (int i2 = 0; i2 < 4; i2++) {
      const float* er = erow + (size_t)i2 * 512;
      float2 e0 = *(const float2*)(er);
      float2 e1 = *(const float2*)(er + 128);
      float2 e2 = *(const float2*)(er + 256);
      float2 e3 = *(const float2*)(er + 384);
      float s0 = v2.x * tanh_f(p.x + e0.x) + v2.y * tanh_f(p.y + e0.y);
      float s1 = v2.x * tanh_f(p.x + e1.x) + v2.y * tanh_f(p.y + e1.y);
      float s2 = v2.x * tanh_f(p.x + e2.x) + v2.y * tanh_f(p.y + e2.y);
      float s3 = v2.x * tanh_f(p.x + e3.x) + v2.y * tanh_f(p.y + e3.y);
      for (int off = 32; off > 0; off >>= 1) {
        s0 += __shfl_down(s0, off, 64);
        s1 += __shfl_down(s1, off, 64);
        s2 += __shfl_down(s2, off, 64);
        s3 += __shfl_down(s3, off, 64);
      }
      if (lane == 0) {
        int t = tb + i2 * 4;
        stw(&u_buf[b * 1024 + t],     (chars[b * 1024 + t]     != 0) ? s0 : 0.0f);
        stw(&u_buf[b * 1024 + t + 1], (chars[b * 1024 + t + 1] != 0) ? s1 : 0.0f);
        stw(&u_buf[b * 1024 + t + 2], (chars[b * 1024 + t + 2] != 0) ? s2 : 0.0f);
        stw(&u_buf[b * 1024 + t + 3], (chars[b * 1024 + t + 3] != 0) ? s3 : 0.0f);
      }
    }
  }
  gbar(ibase, 4);

  // ---------------- P5: softmax + context partials (16 chunks of 64 t) ----------------
  {
    const int b = g >> 4, tch = g & 15;
    float* redm = sh;          // 256
    float* sc   = sh + 256;    // 64
    float* red4 = sh + 320;    // 2048
    float4 uv = *(const float4*)(u_buf + b * 1024 + tid * 4);
    float m = fmaxf(fmaxf(uv.x, uv.y), fmaxf(uv.z, uv.w));
    redm[tid] = m;
    __syncthreads();
    for (int s = 128; s > 0; s >>= 1) { if (tid < s) redm[tid] = fmaxf(redm[tid], redm[tid + s]); __syncthreads(); }
    float M = redm[0];
    __syncthreads();
    float e0 = __expf(uv.x - M), e1 = __expf(uv.y - M), e2 = __expf(uv.z - M), e3 = __expf(uv.w - M);
    redm[tid] = e0 + e1 + e2 + e3;
    __syncthreads();
    for (int s = 128; s > 0; s >>= 1) { if (tid < s) redm[tid] += redm[tid + s]; __syncthreads(); }
    float inv = 1.0f / redm[0];
    if (tch == 0) {
      float4 r; r.x = e0 * inv; r.y = e1 * inv; r.z = e2 * inv; r.w = e3 * inv;
      *(float4*)(scores_o + b * 1024 + tid * 4) = r;
    }
    if (tid < 64) sc[tid] = __expf(u_buf[b * 1024 + tch * 64 + tid] - M) * inv;
    __syncthreads();
    float acc0 = 0, acc1 = 0, acc2 = 0, acc3 = 0, acc4 = 0, acc5 = 0, acc6 = 0, acc7 = 0;
    const float* base = es + ((size_t)b * 1024 + tch * 64) * 512 + lane * 8;
    for (int i = 0; i < 16; i += 2) {
      int t1 = 4 * i + w, t2 = t1 + 4;
      float4 wa1 = *(const float4*)(base + (size_t)t1 * 512);
      float4 wb1 = *(const float4*)(base + (size_t)t1 * 512 + 4);
      float4 wa2 = *(const float4*)(base + (size_t)t2 * 512);
      float4 wb2 = *(const float4*)(base + (size_t)t2 * 512 + 4);
      float s1 = sc[t1], s2 = sc[t2];
      acc0 += s1 * wa1.x + s2 * wa2.x; acc1 += s1 * wa1.y + s2 * wa2.y;
      acc2 += s1 * wa1.z + s2 * wa2.z; acc3 += s1 * wa1.w + s2 * wa2.w;
      acc4 += s1 * wb1.x + s2 * wb2.x; acc5 += s1 * wb1.y + s2 * wb2.y;
      acc6 += s1 * wb1.z + s2 * wb2.z; acc7 += s1 * wb1.w + s2 * wb2.w;
    }
    float* rr = red4 + w * 512 + lane * 8;
    rr[0] = acc0; rr[1] = acc1; rr[2] = acc2; rr[3] = acc3;
    rr[4] = acc4; rr[5] = acc5; rr[6] = acc6; rr[7] = acc7;
    __syncthreads();
    int d0 = tid * 2;
    float r0 = red4[d0] + red4[512 + d0] + red4[1024 + d0] + red4[1536 + d0];
    float r1 = red4[d0 + 1] + red4[512 + d0 + 1] + red4[1024 + d0 + 1] + red4[1536 + d0 + 1];
    atomicAdd(&ctxq[(d0 >> 2) * 256 + b * 4 + (d0 & 3)], r0);
    atomicAdd(&ctxq[((d0 + 1) >> 2) * 256 + b * 4 + ((d0 + 1) & 3)], r1);
  }
  gbar(ibase, 5);

  // ---------------- P6: x = concat(ctx, attn_h) @ ri_w.T + ri_b ; ctx_o ----------------
  if (g < 512) {
    const int n = g;
    if (tid < 160) ((float4*)sh)[tid] = ((const float4*)(ri_w + (size_t)n * 640))[tid];
    if (tid < 64) ctx_o[tid * 512 + n] = ctxq[(n >> 2) * 256 + tid * 4 + (n & 3)];
    __syncthreads();
    float acc = 0.0f;
    for (int k4 = w * 40; k4 < w * 40 + 40; k4++) {
      float4 wv = ((float4*)sh)[k4];
      float4 x4 = (k4 < 128) ? ctxq4[k4 * 64 + lane] : ahq_h4[(k4 - 128) * 64 + lane];
      acc += x4.x * wv.x + x4.y * wv.y + x4.z * wv.z + x4.w * wv.w;
    }
    sh[640 + w * 64 + lane] = acc;
    __syncthreads();
    if (tid < 64) stw(&xq[(n >> 2) * 256 + tid * 4 + (n & 3)],
                      ri_b[n] + sh[640 + tid] + sh[704 + tid] + sh[768 + tid] + sh[832 + tid]);
  }
  gbar(ibase, 6);

  // ---------------- P7: LSTM1 mm + gates fused (block g<512, wave w -> row g+512w) ----------------
  if (g < 512) {
    const int n = g + (w << 9);
    {
      const float4* si = (const float4*)(l1_w_ih + (size_t)n * 512);
      const float4* sh4 = (const float4*)(l1_w_hh + (size_t)n * 512);
      float4* di = (float4*)sh + w * 256;
      float4* dh = di + 128;
      #pragma unroll
      for (int q = 0; q < 2; q++) { di[q * 64 + lane] = si[q * 64 + lane]; dh[q * 64 + lane] = sh4[q * 64 + lane]; }
    }
    __syncthreads();
    const float4* di = (const float4*)sh + w * 256;
    const float4* dh = di + 128;
    float acc = l1_b_ih[n] + l1_b_hh[n];
    #pragma unroll 4
    for (int k4 = 0; k4 < 128; k4++) {
      float4 x4 = xq4[k4 * 64 + lane];
      float4 wv = di[k4];
      acc += x4.x * wv.x + x4.y * wv.y + x4.z * wv.z + x4.w * wv.w;
    }
    #pragma unroll 4
    for (int k4 = 0; k4 < 128; k4++) {
      float4 x4 = hq14[k4 * 64 + lane];
      float4 wv = dh[k4];
      acc += x4.x * wv.x + x4.y * wv.y + x4.z * wv.z + x4.w * wv.w;
    }
    sh[4096 + w * 64 + lane] = acc;
    __syncthreads();
    if (tid < 64) {
      float gi = sh[4096 + tid], gf = sh[4160 + tid], gg = sh[4224 + tid], go = sh[4288 + tid];
      float c = c1pT[g * 64 + tid];
      float c2 = sigm(gf) * c + sigm(gi) * tanh_f(gg);
      float h2v = sigm(go) * tanh_f(c2);
      h1_o[tid * 512 + g] = h2v;
      c1_o[tid * 512 + g] = c2;
      stw(&x2q[(g >> 2) * 256 + tid * 4 + (g & 3)],
          xq[(g >> 2) * 256 + tid * 4 + (g & 3)] + h2v);
    }
  }
  gbar(ibase, 7);

  // ---------------- P8: LSTM2 mm + gates fused ----------------
  if (g < 512) {
    const int n = g + (w << 9);
    {
      const float4* si = (const float4*)(l2_w_ih + (size_t)n * 512);
      const float4* sh4 = (const float4*)(l2_w_hh + (size_t)n * 512);
      float4* di = (float4*)sh + w * 256;
      float4* dh = di + 128;
      #pragma unroll
      for (int q = 0; q < 2; q++) { di[q * 64 + lane] = si[q * 64 + lane]; dh[q * 64 + lane] = sh4[q * 64 + lane]; }
    }
    __syncthreads();
    const float4* di = (const float4*)sh + w * 256;
    const float4* dh = di + 128;
    float acc = l2_b_ih[n] + l2_b_hh[n];
    #pragma unroll 4
    for (int k4 = 0; k4 < 128; k4++) {
      float4 x4 = x2q4[k4 * 64 + lane];
      float4 wv = di[k4];
      acc += x4.x * wv.x + x4.y * wv.y + x4.z * wv.z + x4.w * wv.w;
    }
    #pragma unroll 4
    for (int k4 = 0; k4 < 128; k4++) {
      float4 x4 = hq24[k4 * 64 + lane];
      float4 wv = dh[k4];
      acc += x4.x * wv.x + x4.y * wv.y + x4.z * wv.z + x4.w * wv.w;
    }
    sh[4096 + w * 64 + lane] = acc;
    __syncthreads();
    if (tid < 64) {
      float gi = sh[4096 + tid], gf = sh[4160 + tid], gg = sh[4224 + tid], go = sh[4288 + tid];
      float c = c2pT[g * 64 + tid];
      float c2 = sigm(gf) * c + sigm(gi) * tanh_f(gg);
      float h2v = sigm(go) * tanh_f(c2);
      h2_o[tid * 512 + g] = h2v;
      c2_o[tid * 512 + g] = c2;
      stw(&x3q[(g >> 2) * 256 + tid * 4 + (g & 3)],
          x2q[(g >> 2) * 256 + tid * 4 + (g & 3)] + h2v);
    }
  }
  gbar(ibase, 8);

  // ---------------- P9: mels (80 blocks) + stop (1 block) ----------------
  if (g < 80) {
    const int m = g;
    if (tid < 128) ((float4*)sh)[tid] = ((const float4*)(mp_w + (size_t)m * 20 * 512))[tid];
    __syncthreads();
    float acc = 0.0f;
    for (int k4 = w * 32; k4 < w * 32 + 32; k4++) {
      float4 x4 = x3q4[k4 * 64 + lane];
      float4 wv = ((float4*)sh)[k4];
      acc += x4.x * wv.x + x4.y * wv.y + x4.z * wv.z + x4.w * wv.w;
    }
    sh[512 + w * 64 + lane] = acc;
    __syncthreads();
    if (tid < 64) mels_o[tid * 80 + m] = sh[512 + tid] + sh[576 + tid] + sh[640 + tid] + sh[704 + tid];
  } else if (g == 80) {
    ((float4*)sh)[tid] = ((const float4*)sp_w)[tid];   // 1024 floats
    __syncthreads();
    float acc = 0.0f;
    for (int k4 = w * 32; k4 < w * 32 + 32; k4++) {
      float4 x4 = x3q4[k4 * 64 + lane];
      float4 c4 = ctxq4[k4 * 64 + lane];
      float4 w1 = ((float4*)sh)[k4];
      float4 w2 = ((float4*)sh)[128 + k4];
      acc += x4.x * w1.x + x4.y * w1.y + x4.z * w1.z + x4.w * w1.w;
      acc += c4.x * w2.x + c4.y * w2.y + c4.z * w2.z + c4.w * w2.w;
    }
    sh[1024 + w * 64 + lane] = acc;
    __syncthreads();
    if (tid < 64) stop_o[tid] = sigm(sp_b[0] + sh[1024 + tid] + sh[1088 + tid] + sh[1152 + tid] + sh[1216 + tid]);
  }
}

// =================================================================
extern "C" void kernel_launch(void* const* d_in, const int* in_sizes, int n_in,
                              void* d_out, int out_size, void* d_ws, size_t ws_size,
                              hipStream_t stream) {
  const float* es          = (const float*)d_in[0];
  const float* esp         = (const float*)d_in[1];
  const float* prenet_in   = (const float*)d_in[2];
  const float* attn_hidden = (const float*)d_in[3];
  const float* rnn1_hidden = (const float*)d_in[4];
  const float* rnn2_hidden = (const float*)d_in[5];
  const float* rnn1_cell   = (const float*)d_in[6];
  const float* rnn2_cell   = (const float*)d_in[7];
  const float* context_vec = (const float*)d_in[8];
  const int* chars         = (const int*)d_in[9];
  // d_in[10] = t (unused), d_in[11] = conv_w (unused: conv input is zeros)
  const float* conv_b = (const float*)d_in[12];
  const float* L_w    = (const float*)d_in[13];
  const float* W_w    = (const float*)d_in[14];
  const float* W_b    = (const float*)d_in[15];
  const float* v_w    = (const float*)d_in[16];
  const float* fc1_w  = (const float*)d_in[17];
  const float* fc1_b  = (const float*)d_in[18];
  const float* fc2_w  = (const float*)d_in[19];
  const float* fc2_b  = (const float*)d_in[20];
  const float* gru_w_ih = (const float*)d_in[21];
  const float* gru_w_hh = (const float*)d_in[22];
  const float* gru_b_ih = (const float*)d_in[23];
  const float* gru_b_hh = (const float*)d_in[24];
  const float* ri_w   = (const float*)d_in[25];
  const float* ri_b   = (const float*)d_in[26];
  const float* l1_w_ih = (const float*)d_in[27];
  const float* l1_w_hh = (const float*)d_in[28];
  const float* l1_b_ih = (const float*)d_in[29];
  const float* l1_b_hh = (const float*)d_in[30];
  const float* l2_w_ih = (const float*)d_in[31];
  const float* l2_w_hh = (const float*)d_in[32];
  const float* l2_b_ih = (const float*)d_in[33];
  const float* l2_b_hh = (const float*)d_in[34];
  const float* mp_w = (const float*)d_in[35];
  const float* sp_w = (const float*)d_in[36];
  const float* sp_b = (const float*)d_in[37];

  float* out = (float*)d_out;
  float* ws = (float*)d_ws;

  float* mels_o   = out + 0;
  float* scores_o = out + 5120;
  float* attn_o   = out + 70656;
  float* h1_o     = out + 78848;
  float* h2_o     = out + 111616;
  float* c1_o     = out + 144384;
  float* c2_o     = out + 177152;
  float* ctx_o    = out + 209920;
  float* stop_o   = out + 242688;

  k0<<<1, 256, 0, stream>>>((int*)ws);
  kM<<<NB, 256, 0, stream>>>(es, esp, prenet_in, rnn1_hidden, rnn2_hidden,
                             rnn1_cell, rnn2_cell, context_vec, attn_hidden, chars,
                             conv_b, L_w, W_w, W_b, v_w,
                             fc1_w, fc1_b, fc2_w, fc2_b,
                             gru_w_ih, gru_w_hh, gru_b_ih, gru_b_hh,
                             ri_w, ri_b,
                             l1_w_ih, l1_w_hh, l1_b_ih, l1_b_hh,
                             l2_w_ih, l2_w_hh, l2_b_ih, l2_b_hh,
                             mp_w, sp_w, sp_b,
                             ws,
                             mels_o, scores_o, attn_o, h1_o, h2_o,
                             c1_o, c2_o, ctx_o, stop_o);
}

// Round 8
// 411.580 us; speedup vs baseline: 1.0513x; 1.0513x over previous
//
#include <hip/hip_runtime.h>
#include <stdint.h>

#define JAX_PARTITIONABLE 1
#define NB 1024

// ---------- helpers ----------
__device__ __forceinline__ float tanh_f(float x) {
  float e = __expf(2.0f * x);
  return 1.0f - 2.0f / (e + 1.0f);
}
__device__ __forceinline__ float sigm(float x) {
  return 1.0f / (1.0f + __expf(-x));
}

// Workspace stores: agent-scope relaxed atomic stores (sc1 write-through to the
// coherent memory side). Consumers use PLAIN loads after the barrier; first touch
// of each line is always post-barrier (write-once-then-read dataflow), hence fresh.
__device__ __forceinline__ void stw(float* p, float v) {
  __hip_atomic_store(p, v, __ATOMIC_RELAXED, __HIP_MEMORY_SCOPE_AGENT);
}
__device__ __forceinline__ void stw4(float* p, float4 v) {
  union { float2 f; uint64_t u; } a, b;
  a.f.x = v.x; a.f.y = v.y; b.f.x = v.z; b.f.y = v.w;
  __hip_atomic_store((uint64_t*)p, a.u, __ATOMIC_RELAXED, __HIP_MEMORY_SCOPE_AGENT);
  __hip_atomic_store(((uint64_t*)p) + 1, b.u, __ATOMIC_RELAXED, __HIP_MEMORY_SCOPE_AGENT);
}

// ---------- Threefry-2x32 (JAX-compatible) ----------
__device__ __forceinline__ void tf2x32(unsigned k0, unsigned k1, unsigned x0, unsigned x1,
                                       unsigned &o0, unsigned &o1) {
  unsigned ks0 = k0, ks1 = k1, ks2 = k0 ^ k1 ^ 0x1BD11BDAu;
  x0 += ks0; x1 += ks1;
#define RR(r) { x0 += x1; x1 = (x1 << r) | (x1 >> (32 - r)); x1 ^= x0; }
  RR(13) RR(15) RR(26) RR(6)  x0 += ks1; x1 += ks2 + 1u;
  RR(17) RR(29) RR(16) RR(24) x0 += ks2; x1 += ks0 + 2u;
  RR(13) RR(15) RR(26) RR(6)  x0 += ks0; x1 += ks1 + 3u;
  RR(17) RR(29) RR(16) RR(24) x0 += ks1; x1 += ks2 + 4u;
  RR(13) RR(15) RR(26) RR(6)  x0 += ks2; x1 += ks0 + 5u;
#undef RR
  o0 = x0; o1 = x1;
}

__device__ __forceinline__ float drop_scale(unsigned k0, unsigned k1, unsigned flat) {
#if JAX_PARTITIONABLE
  unsigned o0, o1; tf2x32(k0, k1, 0u, flat, o0, o1);
  unsigned bits = o0 ^ o1;
#else
  unsigned o0, o1, bits;
  if (flat < 8192u) { tf2x32(k0, k1, flat, flat + 8192u, o0, o1); bits = o0; }
  else             { tf2x32(k0, k1, flat - 8192u, flat, o0, o1); bits = o1; }
#endif
  return (bits >> 31) ? 0.0f : 2.0f;
}
__device__ __forceinline__ void get_drop_keys(unsigned &a0, unsigned &a1,
                                              unsigned &b0, unsigned &b1) {
#if JAX_PARTITIONABLE
  tf2x32(0u, 42u, 0u, 0u, a0, a1);
  tf2x32(0u, 42u, 0u, 1u, b0, b1);
#else
  unsigned p0, q0, p1, q1;
  tf2x32(0u, 42u, 0u, 2u, p0, q0);
  tf2x32(0u, 42u, 1u, 3u, p1, q1);
  a0 = p0; a1 = p1; b0 = q0; b1 = q1;
#endif
}

// ---------- store-based device barrier: ZERO atomic RMWs ----------
// Arrival: each block sc1-stores `phase` to its OWN flag word (no same-address
// serialization — the suspected 5-13us/barrier cost of RMW trees in R4-R7).
// Checker (block 0): 256 threads sweep all 1024 arrival words with coalesced
// int loads (~0.5us/sweep), then threads 0-31 store `phase` to 32 distributed
// release lines. Waiters relax-poll their release line. All values monotonic
// within a run; k0 re-zeroes before each replay. Bounded spins -> numeric
// failure, not hang.
__device__ __forceinline__ void gbar(int* ibase, int phase) {
  __syncthreads();
  int* arrival = ibase;          // 1024 words
  int* release = ibase + 1024;   // 32 lines x 64 ints
  if (threadIdx.x == 0)
    __hip_atomic_store(arrival + blockIdx.x, phase, __ATOMIC_RELAXED, __HIP_MEMORY_SCOPE_AGENT);
  if (blockIdx.x == 0) {
    __shared__ int notdone;
    const int t4 = threadIdx.x * 4;
    long long guard = 0;
    for (;;) {
      int a0 = __hip_atomic_load(arrival + t4 + 0, __ATOMIC_RELAXED, __HIP_MEMORY_SCOPE_AGENT);
      int a1 = __hip_atomic_load(arrival + t4 + 1, __ATOMIC_RELAXED, __HIP_MEMORY_SCOPE_AGENT);
      int a2 = __hip_atomic_load(arrival + t4 + 2, __ATOMIC_RELAXED, __HIP_MEMORY_SCOPE_AGENT);
      int a3 = __hip_atomic_load(arrival + t4 + 3, __ATOMIC_RELAXED, __HIP_MEMORY_SCOPE_AGENT);
      bool ok = (a0 >= phase) && (a1 >= phase) && (a2 >= phase) && (a3 >= phase);
      if (threadIdx.x == 0) notdone = 0;
      __syncthreads();
      if (!ok) notdone = 1;
      __syncthreads();
      if (!notdone) break;
      if (++guard > (1LL << 19)) break;
      __builtin_amdgcn_s_sleep(2);
    }
    if (threadIdx.x < 32)
      __hip_atomic_store(release + threadIdx.x * 64, phase, __ATOMIC_RELAXED, __HIP_MEMORY_SCOPE_AGENT);
  } else if (threadIdx.x == 0) {
    int* myrel = release + (int)(blockIdx.x & 31) * 64;
    long long guard = 0;
    while (__hip_atomic_load(myrel, __ATOMIC_RELAXED, __HIP_MEMORY_SCOPE_AGENT) < phase) {
      __builtin_amdgcn_s_sleep(2);
      if (++guard > (1LL << 21)) break;
    }
  }
  __syncthreads();
}

// =================================================================
// k0: zero arrival + release words (ws is poisoned between iterations)
// =================================================================
__global__ void k0(int* cnt) {
  for (int i = threadIdx.x; i < 3072; i += 256) cnt[i] = 0;
}

// =================================================================
// kM: whole decoder step, 9 phases / 8 grid barriers, 1024 blocks (4/CU)
// Activations packed as [k/4][b][4]: lane b loads float4 of 4 consecutive k.
// No es/esp warming: their consumers (P4/P5) are fully-coalesced streams that
// run at HBM peak on cold data. Weights+chars still warmed in P2 (their
// consumers are short latency-bound stage chains).
// =================================================================
__global__ __launch_bounds__(256, 4) void kM(
    const float* es, const float* esp, const float* prenet_in,
    const float* rnn1_hidden, const float* rnn2_hidden,
    const float* rnn1_cell, const float* rnn2_cell,
    const float* context_vec, const float* attn_hidden, const int* chars,
    const float* conv_b, const float* L_w, const float* W_w, const float* W_b, const float* v_w,
    const float* fc1_w, const float* fc1_b, const float* fc2_w, const float* fc2_b,
    const float* gru_w_ih, const float* gru_w_hh, const float* gru_b_ih, const float* gru_b_hh,
    const float* ri_w, const float* ri_b,
    const float* l1_w_ih, const float* l1_w_hh, const float* l1_b_ih, const float* l1_b_hh,
    const float* l2_w_ih, const float* l2_w_hh, const float* l2_b_ih, const float* l2_b_hh,
    const float* mp_w, const float* sp_w, const float* sp_b,
    float* ws,
    float* mels_o, float* scores_o, float* attn_o, float* h1_o, float* h2_o,
    float* c1_o, float* c2_o, float* ctx_o, float* stop_o) {
  int* ibase = (int*)ws;            // 3072+ ints: 1024 arrival + 32x64 release
  float* pqc    = ws + 4160;        // 128
  float* phq    = ws + 4288;        // 16384  [64][64][4]
  float* poq    = ws + 20672;       // 16384
  float* ahq_h  = ws + 37056;       // 8192   [32][64][4] attn_h (GRU out)
  float* u_buf  = ws + 45248;       // 65536
  float* ctxq   = ws + 110784;      // 32768  [128][64][4] (atomic-accum; zeroed P1)
  float* xq     = ws + 143552;      // 32768
  float* x2q    = ws + 176320;      // 32768
  float* x3q    = ws + 209088;      // 32768
  float* hq1    = ws + 241856;      // 32768
  float* hq2    = ws + 274624;      // 32768
  float* cvq    = ws + 307392;      // 32768
  float* ahq_in = ws + 340160;      // 8192
  float* c1pT   = ws + 348352;      // 32768  [k][b]
  float* c2pT   = ws + 381120;      // 32768

  const float4* cvq4   = (const float4*)cvq;
  const float4* phq4   = (const float4*)phq;
  const float4* poq4   = (const float4*)poq;
  const float4* ahq_in4= (const float4*)ahq_in;
  const float4* ahq_h4 = (const float4*)ahq_h;
  const float4* ctxq4  = (const float4*)ctxq;
  const float4* xq4    = (const float4*)xq;
  const float4* x2q4   = (const float4*)x2q;
  const float4* x3q4   = (const float4*)x3q;
  const float4* hq14   = (const float4*)hq1;
  const float4* hq24   = (const float4*)hq2;

  const int g = blockIdx.x, tid = threadIdx.x;
  const int w = tid >> 6, lane = tid & 63;
  __shared__ float sh[5440];        // 21.8 KB -> 4 blocks/CU co-resident

  // ---------------- P1: fc1 + packed transposes + zero ctxq + pqc ----------------
  if (g < 64) {
    for (int i = tid; i < 5120; i += 256) sh[(i / 80) * 81 + (i % 80)] = prenet_in[i];
    __syncthreads();
    unsigned d1k0, d1k1, d2k0, d2k1;
    get_drop_keys(d1k0, d1k1, d2k0, d2k1);
    const int j = g * 4 + w;
    float acc = fc1_b[j];
    const float* wr = fc1_w + j * 80;
    #pragma unroll 8
    for (int k = 0; k < 80; k += 2) {
      float2 wv = *(const float2*)(wr + k);
      acc += sh[lane * 81 + k] * wv.x + sh[lane * 81 + k + 1] * wv.y;
    }
    acc = fmaxf(acc, 0.0f) * drop_scale(d1k0, d1k1, (unsigned)(lane * 256 + j));
    stw(&phq[g * 256 + lane * 4 + w], acc);
  } else if (g < 96) {          // hq1
    int t = (g - 64) * 256 + tid;
    int k4 = t >> 6, b = t & 63;
    stw4(&hq1[k4 * 256 + b * 4], ((const float4*)rnn1_hidden)[b * 128 + k4]);
  } else if (g < 128) {         // hq2
    int t = (g - 96) * 256 + tid;
    int k4 = t >> 6, b = t & 63;
    stw4(&hq2[k4 * 256 + b * 4], ((const float4*)rnn2_hidden)[b * 128 + k4]);
  } else if (g < 160) {         // cvq
    int t = (g - 128) * 256 + tid;
    int k4 = t >> 6, b = t & 63;
    stw4(&cvq[k4 * 256 + b * 4], ((const float4*)context_vec)[b * 128 + k4]);
  } else if (g < 168) {         // ahq_in
    int t = (g - 160) * 256 + tid;
    int k4 = t >> 6, b = t & 63;
    stw4(&ahq_in[k4 * 256 + b * 4], ((const float4*)attn_hidden)[b * 32 + k4]);
  } else if (g < 232) {         // c1pT [k][b]
    int base = (g - 168) * 512;
    #pragma unroll
    for (int e = 0; e < 2; e++) { int i = base + tid + e * 256; stw(&c1pT[i], rnn1_cell[(i & 63) * 512 + (i >> 6)]); }
  } else if (g < 296) {         // c2pT
    int base = (g - 232) * 512;
    #pragma unroll
    for (int e = 0; e < 2; e++) { int i = base + tid + e * 256; stw(&c2pT[i], rnn2_cell[(i & 63) * 512 + (i >> 6)]); }
  } else if (g < 360) {         // zero ctxq
    int base = (g - 296) * 512;
    #pragma unroll
    for (int e = 0; e < 2; e++) stw(&ctxq[base + tid + e * 256], 0.0f);
  } else if (g == 360) {        // pqc
    if (tid < 128) {
      float acc = W_b[tid];
      const float* lw = L_w + tid * 32;
      #pragma unroll
      for (int f = 0; f < 32; f++) acc += conv_b[f] * lw[f];
      stw(&pqc[tid], acc);
    }
  }
  gbar(ibase, 1);

  // ---------------- P2: fc2 | idle blocks warm weights + chars ----------------
  if (g < 64) {
    const int j = g * 4 + w;
    ((float4*)(sh + w * 256))[lane] = ((const float4*)(fc2_w + j * 256))[lane];
    __syncthreads();
    unsigned d1k0, d1k1, d2k0, d2k1;
    get_drop_keys(d1k0, d1k1, d2k0, d2k1);
    const float4* wv4 = (const float4*)(sh + w * 256);
    float acc = fc2_b[j];
    #pragma unroll 8
    for (int k4 = 0; k4 < 64; k4++) {
      float4 x4 = phq4[k4 * 64 + lane];
      float4 wv = wv4[k4];
      acc += x4.x * wv.x + x4.y * wv.y + x4.z * wv.z + x4.w * wv.w;
    }
    acc = fmaxf(acc, 0.0f) * drop_scale(d2k0, d2k1, (unsigned)(lane * 256 + j));
    stw(&poq[g * 256 + lane * 4 + w], acc);
  } else {
    const unsigned wid = (unsigned)((g - 64) * 256 + tid);   // 0..245759
    float acc = 0.0f;
    if (wid < 32768u) {
      acc += l1_w_ih[(size_t)wid * 32];
      acc += l1_w_hh[(size_t)wid * 32];
      acc += l2_w_ih[(size_t)wid * 32];
      acc += l2_w_hh[(size_t)wid * 32];
    }
    if (wid < 10240u) acc += ri_w[(size_t)wid * 32];
    if (wid < 9216u)  acc += gru_w_ih[(size_t)wid * 32];
    if (wid < 1536u)  acc += gru_w_hh[(size_t)wid * 32];
    if (wid < 512u)   acc += W_w[(size_t)wid * 32];
    if (wid < 2048u)  acc += (float)chars[(size_t)wid * 32];
    if (wid < 1280u)  acc += mp_w[(size_t)(wid >> 4) * 10240 + (wid & 15) * 32];
    if (wid < 32u)    acc += sp_w[(size_t)wid * 32];
    asm volatile("" :: "v"(acc));
  }
  gbar(ibase, 2);

  // ---------------- P3: GRU mm + gates fused (blocks 0-127) ----------------
  if (g < 128) {
    if (w < 3) {
      const int rj = g + 128 * w;
      const float4* src = (const float4*)(gru_w_ih + (size_t)rj * 768);
      float4* dst = (float4*)(sh + w * 768);
      #pragma unroll
      for (int q = 0; q < 3; q++) dst[q * 64 + lane] = src[q * 64 + lane];
    } else {
      float4* dst = (float4*)(sh + 2304);
      if (lane < 32) {
        dst[lane]      = ((const float4*)gru_w_hh)[(size_t)g * 32 + lane];
        dst[32 + lane] = ((const float4*)gru_w_hh)[(size_t)(128 + g) * 32 + lane];
        dst[64 + lane] = ((const float4*)gru_w_hh)[(size_t)(256 + g) * 32 + lane];
      }
    }
    __syncthreads();
    if (w < 3) {
      const int rj = g + 128 * w;
      const float4* wv4 = (const float4*)(sh + w * 768);
      float acc = gru_b_ih[rj];
      #pragma unroll 4
      for (int k4 = 0; k4 < 128; k4++) {
        float4 x4 = cvq4[k4 * 64 + lane];
        float4 wv = wv4[k4];
        acc += x4.x * wv.x + x4.y * wv.y + x4.z * wv.z + x4.w * wv.w;
      }
      #pragma unroll 4
      for (int k4 = 0; k4 < 64; k4++) {
        float4 x4 = poq4[k4 * 64 + lane];
        float4 wv = wv4[128 + k4];
        acc += x4.x * wv.x + x4.y * wv.y + x4.z * wv.z + x4.w * wv.w;
      }
      sh[2688 + w * 64 + lane] = acc;
    } else {
      const float4* wh4 = (const float4*)(sh + 2304);
      #pragma unroll
      for (int r = 0; r < 3; r++) {
        float acc = gru_b_hh[r * 128 + g];
        #pragma unroll 4
        for (int k4 = 0; k4 < 32; k4++) {
          float4 x4 = ahq_in4[k4 * 64 + lane];
          float4 wv = wh4[r * 32 + k4];
          acc += x4.x * wv.x + x4.y * wv.y + x4.z * wv.z + x4.w * wv.w;
        }
        sh[2688 + (3 + r) * 64 + lane] = acc;
      }
    }
    __syncthreads();
    if (tid < 64) {
      float gr = sh[2688 + tid]       + sh[2688 + 192 + tid];
      float gz = sh[2688 + 64 + tid]  + sh[2688 + 256 + tid];
      float gin = sh[2688 + 128 + tid];
      float ghn = sh[2688 + 320 + tid];
      float a0 = ahq_in[(g >> 2) * 256 + tid * 4 + (g & 3)];
      float r = sigm(gr), z = sigm(gz);
      float h = (1.0f - z) * tanh_f(gin + r * ghn) + z * a0;
      stw(&ahq_h[(g >> 2) * 256 + tid * 4 + (g & 3)], h);
      attn_o[tid * 128 + g] = h;
    }
  }
  gbar(ibase, 3);

  // ---------------- P4: per-lane pq + u (16 chunks of 64 t) ----------------
  {
    const int b = g >> 4, tch = g & 15;
    float* shh = sh;           // 128
    float* pqs = sh + 128;     // 128
    if (tid < 128) shh[tid] = ahq_h[(tid >> 2) * 256 + b * 4 + (tid & 3)];
    __syncthreads();
    if (tid < 128) {
      const int n = tid;
      float acc = pqc[n];
      const float4* wr = (const float4*)(W_w + n * 128);
      #pragma unroll 8
      for (int k4 = 0; k4 < 32; k4++) {
        float4 wv = wr[k4];
        acc += shh[k4 * 4] * wv.x + shh[k4 * 4 + 1] * wv.y + shh[k4 * 4 + 2] * wv.z + shh[k4 * 4 + 3] * wv.w;
      }
      pqs[n] = acc;
    }
    __syncthreads();
    float2 p = *(const float2*)(pqs + 2 * lane);
    float2 v2 = *(const float2*)(v_w + 2 * lane);
    const int tb = tch * 64 + w * 16;
    const float* erow = esp + ((size_t)b * 1024 + tb) * 128 + 2 * lane;
    for (int i2 = 0; i2 < 4; i2++) {
      const float* er = erow + (size_t)i2 * 512;
      float2 e0 = *(const float2*)(er);
      float2 e1 = *(const float2*)(er + 128);
      float2 e2 = *(const float2*)(er + 256);
      float2 e3 = *(const float2*)(er + 384);
      float s0 = v2.x * tanh_f(p.x + e0.x) + v2.y * tanh_f(p.y + e0.y);
      float s1 = v2.x * tanh_f(p.x + e1.x) + v2.y * tanh_f(p.y + e1.y);
      float s2 = v2.x * tanh_f(p.x + e2.x) + v2.y * tanh_f(p.y + e2.y);
      float s3 = v2.x * tanh_f(p.x + e3.x) + v2.y * tanh_f(p.y + e3.y);
      for (int off = 32; off > 0; off >>= 1) {
        s0 += __shfl_down(s0, off, 64);
        s1 += __shfl_down(s1, off, 64);
        s2 += __shfl_down(s2, off, 64);
        s3 += __shfl_down(s3, off, 64);
      }
      if (lane == 0) {
        int t = tb + i2 * 4;
        stw(&u_buf[b * 1024 + t],     (chars[b * 1024 + t]     != 0) ? s0 : 0.0f);
        stw(&u_buf[b * 1024 + t + 1], (chars[b * 1024 + t + 1] != 0) ? s1 : 0.0f);
        stw(&u_buf[b * 1024 + t + 2], (chars[b * 1024 + t + 2] != 0) ? s2 : 0.0f);
        stw(&u_buf[b * 1024 + t + 3], (chars[b * 1024 + t + 3] != 0) ? s3 : 0.0f);
      }
    }
  }
  gbar(ibase, 4);

  // ---------------- P5: softmax + context partials (16 chunks of 64 t) ----------------
  {
    const int b = g >> 4, tch = g & 15;
    float* redm = sh;          // 256
    float* sc   = sh + 256;    // 64
    float* red4 = sh + 320;    // 2048
    float4 uv = *(const float4*)(u_buf + b * 1024 + tid * 4);
    float m = fmaxf(fmaxf(uv.x, uv.y), fmaxf(uv.z, uv.w));
    redm[tid] = m;
    __syncthreads();
    for (int s = 128; s > 0; s >>= 1) { if (tid < s) redm[tid] = fmaxf(redm[tid], redm[tid + s]); __syncthreads(); }
    float M = redm[0];
    __syncthreads();
    float e0 = __expf(uv.x - M), e1 = __expf(uv.y - M), e2 = __expf(uv.z - M), e3 = __expf(uv.w - M);
    redm[tid] = e0 + e1 + e2 + e3;
    __syncthreads();
    for (int s = 128; s > 0; s >>= 1) { if (tid < s) redm[tid] += redm[tid + s]; __syncthreads(); }
    float inv = 1.0f / redm[0];
    if (tch == 0) {
      float4 r; r.x = e0 * inv; r.y = e1 * inv; r.z = e2 * inv; r.w = e3 * inv;
      *(float4*)(scores_o + b * 1024 + tid * 4) = r;
    }
    if (tid < 64) sc[tid] = __expf(u_buf[b * 1024 + tch * 64 + tid] - M) * inv;
    __syncthreads();
    float acc0 = 0, acc1 = 0, acc2 = 0, acc3 = 0, acc4 = 0, acc5 = 0, acc6 = 0, acc7 = 0;
    const float* base = es + ((size_t)b * 1024 + tch * 64) * 512 + lane * 8;
    for (int i = 0; i < 16; i += 2) {
      int t1 = 4 * i + w, t2 = t1 + 4;
      float4 wa1 = *(const float4*)(base + (size_t)t1 * 512);
      float4 wb1 = *(const float4*)(base + (size_t)t1 * 512 + 4);
      float4 wa2 = *(const float4*)(base + (size_t)t2 * 512);
      float4 wb2 = *(const float4*)(base + (size_t)t2 * 512 + 4);
      float s1 = sc[t1], s2 = sc[t2];
      acc0 += s1 * wa1.x + s2 * wa2.x; acc1 += s1 * wa1.y + s2 * wa2.y;
      acc2 += s1 * wa1.z + s2 * wa2.z; acc3 += s1 * wa1.w + s2 * wa2.w;
      acc4 += s1 * wb1.x + s2 * wb2.x; acc5 += s1 * wb1.y + s2 * wb2.y;
      acc6 += s1 * wb1.z + s2 * wb2.z; acc7 += s1 * wb1.w + s2 * wb2.w;
    }
    float* rr = red4 + w * 512 + lane * 8;
    rr[0] = acc0; rr[1] = acc1; rr[2] = acc2; rr[3] = acc3;
    rr[4] = acc4; rr[5] = acc5; rr[6] = acc6; rr[7] = acc7;
    __syncthreads();
    int d0 = tid * 2;
    float r0 = red4[d0] + red4[512 + d0] + red4[1024 + d0] + red4[1536 + d0];
    float r1 = red4[d0 + 1] + red4[512 + d0 + 1] + red4[1024 + d0 + 1] + red4[1536 + d0 + 1];
    atomicAdd(&ctxq[(d0 >> 2) * 256 + b * 4 + (d0 & 3)], r0);
    atomicAdd(&ctxq[((d0 + 1) >> 2) * 256 + b * 4 + ((d0 + 1) & 3)], r1);
  }
  gbar(ibase, 5);

  // ---------------- P6: x = concat(ctx, attn_h) @ ri_w.T + ri_b ; ctx_o ----------------
  if (g < 512) {
    const int n = g;
    if (tid < 160) ((float4*)sh)[tid] = ((const float4*)(ri_w + (size_t)n * 640))[tid];
    if (tid < 64) ctx_o[tid * 512 + n] = ctxq[(n >> 2) * 256 + tid * 4 + (n & 3)];
    __syncthreads();
    float acc = 0.0f;
    for (int k4 = w * 40; k4 < w * 40 + 40; k4++) {
      float4 wv = ((float4*)sh)[k4];
      float4 x4 = (k4 < 128) ? ctxq4[k4 * 64 + lane] : ahq_h4[(k4 - 128) * 64 + lane];
      acc += x4.x * wv.x + x4.y * wv.y + x4.z * wv.z + x4.w * wv.w;
    }
    sh[640 + w * 64 + lane] = acc;
    __syncthreads();
    if (tid < 64) stw(&xq[(n >> 2) * 256 + tid * 4 + (n & 3)],
                      ri_b[n] + sh[640 + tid] + sh[704 + tid] + sh[768 + tid] + sh[832 + tid]);
  }
  gbar(ibase, 6);

  // ---------------- P7: LSTM1 mm + gates fused (block g<512, wave w -> row g+512w) ----------------
  if (g < 512) {
    const int n = g + (w << 9);
    {
      const float4* si = (const float4*)(l1_w_ih + (size_t)n * 512);
      const float4* sh4 = (const float4*)(l1_w_hh + (size_t)n * 512);
      float4* di = (float4*)sh + w * 256;
      float4* dh = di + 128;
      #pragma unroll
      for (int q = 0; q < 2; q++) { di[q * 64 + lane] = si[q * 64 + lane]; dh[q * 64 + lane] = sh4[q * 64 + lane]; }
    }
    __syncthreads();
    const float4* di = (const float4*)sh + w * 256;
    const float4* dh = di + 128;
    float acc = l1_b_ih[n] + l1_b_hh[n];
    #pragma unroll 4
    for (int k4 = 0; k4 < 128; k4++) {
      float4 x4 = xq4[k4 * 64 + lane];
      float4 wv = di[k4];
      acc += x4.x * wv.x + x4.y * wv.y + x4.z * wv.z + x4.w * wv.w;
    }
    #pragma unroll 4
    for (int k4 = 0; k4 < 128; k4++) {
      float4 x4 = hq14[k4 * 64 + lane];
      float4 wv = dh[k4];
      acc += x4.x * wv.x + x4.y * wv.y + x4.z * wv.z + x4.w * wv.w;
    }
    sh[4096 + w * 64 + lane] = acc;
    __syncthreads();
    if (tid < 64) {
      float gi = sh[4096 + tid], gf = sh[4160 + tid], gg = sh[4224 + tid], go = sh[4288 + tid];
      float c = c1pT[g * 64 + tid];
      float c2 = sigm(gf) * c + sigm(gi) * tanh_f(gg);
      float h2v = sigm(go) * tanh_f(c2);
      h1_o[tid * 512 + g] = h2v;
      c1_o[tid * 512 + g] = c2;
      stw(&x2q[(g >> 2) * 256 + tid * 4 + (g & 3)],
          xq[(g >> 2) * 256 + tid * 4 + (g & 3)] + h2v);
    }
  }
  gbar(ibase, 7);

  // ---------------- P8: LSTM2 mm + gates fused ----------------
  if (g < 512) {
    const int n = g + (w << 9);
    {
      const float4* si = (const float4*)(l2_w_ih + (size_t)n * 512);
      const float4* sh4 = (const float4*)(l2_w_hh + (size_t)n * 512);
      float4* di = (float4*)sh + w * 256;
      float4* dh = di + 128;
      #pragma unroll
      for (int q = 0; q < 2; q++) { di[q * 64 + lane] = si[q * 64 + lane]; dh[q * 64 + lane] = sh4[q * 64 + lane]; }
    }
    __syncthreads();
    const float4* di = (const float4*)sh + w * 256;
    const float4* dh = di + 128;
    float acc = l2_b_ih[n] + l2_b_hh[n];
    #pragma unroll 4
    for (int k4 = 0; k4 < 128; k4++) {
      float4 x4 = x2q4[k4 * 64 + lane];
      float4 wv = di[k4];
      acc += x4.x * wv.x + x4.y * wv.y + x4.z * wv.z + x4.w * wv.w;
    }
    #pragma unroll 4
    for (int k4 = 0; k4 < 128; k4++) {
      float4 x4 = hq24[k4 * 64 + lane];
      float4 wv = dh[k4];
      acc += x4.x * wv.x + x4.y * wv.y + x4.z * wv.z + x4.w * wv.w;
    }
    sh[4096 + w * 64 + lane] = acc;
    __syncthreads();
    if (tid < 64) {
      float gi = sh[4096 + tid], gf = sh[4160 + tid], gg = sh[4224 + tid], go = sh[4288 + tid];
      float c = c2pT[g * 64 + tid];
      float c2 = sigm(gf) * c + sigm(gi) * tanh_f(gg);
      float h2v = sigm(go) * tanh_f(c2);
      h2_o[tid * 512 + g] = h2v;
      c2_o[tid * 512 + g] = c2;
      stw(&x3q[(g >> 2) * 256 + tid * 4 + (g & 3)],
          x2q[(g >> 2) * 256 + tid * 4 + (g & 3)] + h2v);
    }
  }
  gbar(ibase, 8);

  // ---------------- P9: mels (80 blocks) + stop (1 block) ----------------
  if (g < 80) {
    const int m = g;
    if (tid < 128) ((float4*)sh)[tid] = ((const float4*)(mp_w + (size_t)m * 20 * 512))[tid];
    __syncthreads();
    float acc = 0.0f;
    for (int k4 = w * 32; k4 < w * 32 + 32; k4++) {
      float4 x4 = x3q4[k4 * 64 + lane];
      float4 wv = ((float4*)sh)[k4];
      acc += x4.x * wv.x + x4.y * wv.y + x4.z * wv.z + x4.w * wv.w;
    }
    sh[512 + w * 64 + lane] = acc;
    __syncthreads();
    if (tid < 64) mels_o[tid * 80 + m] = sh[512 + tid] + sh[576 + tid] + sh[640 + tid] + sh[704 + tid];
  } else if (g == 80) {
    ((float4*)sh)[tid] = ((const float4*)sp_w)[tid];   // 1024 floats
    __syncthreads();
    float acc = 0.0f;
    for (int k4 = w * 32; k4 < w * 32 + 32; k4++) {
      float4 x4 = x3q4[k4 * 64 + lane];
      float4 c4 = ctxq4[k4 * 64 + lane];
      float4 w1 = ((float4*)sh)[k4];
      float4 w2 = ((float4*)sh)[128 + k4];
      acc += x4.x * w1.x + x4.y * w1.y + x4.z * w1.z + x4.w * w1.w;
      acc += c4.x * w2.x + c4.y * w2.y + c4.z * w2.z + c4.w * w2.w;
    }
    sh[1024 + w * 64 + lane] = acc;
    __syncthreads();
    if (tid < 64) stop_o[tid] = sigm(sp_b[0] + sh[1024 + tid] + sh[1088 + tid] + sh[1152 + tid] + sh[1216 + tid]);
  }
}

// =================================================================
extern "C" void kernel_launch(void* const* d_in, const int* in_sizes, int n_in,
                              void* d_out, int out_size, void* d_ws, size_t ws_size,
                              hipStream_t stream) {
  const float* es          = (const float*)d_in[0];
  const float* esp         = (const float*)d_in[1];
  const float* prenet_in   = (const float*)d_in[2];
  const float* attn_hidden = (const float*)d_in[3];
  const float* rnn1_hidden = (const float*)d_in[4];
  const float* rnn2_hidden = (const float*)d_in[5];
  const float* rnn1_cell   = (const float*)d_in[6];
  const float* rnn2_cell   = (const float*)d_in[7];
  const float* context_vec = (const float*)d_in[8];
  const int* chars         = (const int*)d_in[9];
  // d_in[10] = t (unused), d_in[11] = conv_w (unused: conv input is zeros)
  const float* conv_b = (const float*)d_in[12];
  const float* L_w    = (const float*)d_in[13];
  const float* W_w    = (const float*)d_in[14];
  const float* W_b    = (const float*)d_in[15];
  const float* v_w    = (const float*)d_in[16];
  const float* fc1_w  = (const float*)d_in[17];
  const float* fc1_b  = (const float*)d_in[18];
  const float* fc2_w  = (const float*)d_in[19];
  const float* fc2_b  = (const float*)d_in[20];
  const float* gru_w_ih = (const float*)d_in[21];
  const float* gru_w_hh = (const float*)d_in[22];
  const float* gru_b_ih = (const float*)d_in[23];
  const float* gru_b_hh = (const float*)d_in[24];
  const float* ri_w   = (const float*)d_in[25];
  const float* ri_b   = (const float*)d_in[26];
  const float* l1_w_ih = (const float*)d_in[27];
  const float* l1_w_hh = (const float*)d_in[28];
  const float* l1_b_ih = (const float*)d_in[29];
  const float* l1_b_hh = (const float*)d_in[30];
  const float* l2_w_ih = (const float*)d_in[31];
  const float* l2_w_hh = (const float*)d_in[32];
  const float* l2_b_ih = (const float*)d_in[33];
  const float* l2_b_hh = (const float*)d_in[34];
  const float* mp_w = (const float*)d_in[35];
  const float* sp_w = (const float*)d_in[36];
  const float* sp_b = (const float*)d_in[37];

  float* out = (float*)d_out;
  float* ws = (float*)d_ws;

  float* mels_o   = out + 0;
  float* scores_o = out + 5120;
  float* attn_o   = out + 70656;
  float* h1_o     = out + 78848;
  float* h2_o     = out + 111616;
  float* c1_o     = out + 144384;
  float* c2_o     = out + 177152;
  float* ctx_o    = out + 209920;
  float* stop_o   = out + 242688;

  k0<<<1, 256, 0, stream>>>((int*)ws);
  kM<<<NB, 256, 0, stream>>>(es, esp, prenet_in, rnn1_hidden, rnn2_hidden,
                             rnn1_cell, rnn2_cell, context_vec, attn_hidden, chars,
                             conv_b, L_w, W_w, W_b, v_w,
                             fc1_w, fc1_b, fc2_w, fc2_b,
                             gru_w_ih, gru_w_hh, gru_b_ih, gru_b_hh,
                             ri_w, ri_b,
                             l1_w_ih, l1_w_hh, l1_b_ih, l1_b_hh,
                             l2_w_ih, l2_w_hh, l2_b_ih, l2_b_hh,
                             mp_w, sp_w, sp_b,
                             ws,
                             mels_o, scores_o, attn_o, h1_o, h2_o,
                             c1_o, c2_o, ctx_o, stop_o);
}